// Round 10
// baseline (220.056 us; speedup 1.0000x reference)
//
#include <hip/hip_runtime.h>
#include <math.h>

#define NN 50000
#define EE 800000
#define FIN 128
#define HID 64
#define CL 40
#define SCB 256
#define NBLK ((NN + SCB - 1) / SCB)  // 196
#define NREP 8

typedef unsigned short ushort_t;
typedef unsigned int uint_t;
typedef float f32x4 __attribute__((ext_vector_type(4)));
typedef short s16x8 __attribute__((ext_vector_type(8)));

__device__ __forceinline__ ushort_t f2bf(float f) {
  uint_t u = __float_as_uint(f);
  u = (u + 0x7FFFu + ((u >> 16) & 1u)) >> 16;  // RNE
  return (ushort_t)u;
}
__device__ __forceinline__ uint_t f2bf2(float lo, float hi) {
  return (uint_t)f2bf(lo) | ((uint_t)f2bf(hi) << 16);
}
__device__ __forceinline__ float bf2f(ushort_t s) {
  return __uint_as_float(((uint_t)s) << 16);
}
__device__ __forceinline__ float bflo(uint_t u) {
  return __uint_as_float(u << 16);
}
__device__ __forceinline__ float bfhi(uint_t u) {
  return __uint_as_float(u & 0xFFFF0000u);
}

__device__ __forceinline__ int wave_sum_i(int v) {
#pragma unroll
  for (int off = 32; off > 0; off >>= 1) v += __shfl_xor(v, off, 64);
  return v;
}
__device__ __forceinline__ float half_sum(float v) {  // within 32-lane half
#pragma unroll
  for (int off = 16; off > 0; off >>= 1) v += __shfl_xor(v, off, 64);
  return v;
}
__device__ __forceinline__ float half_max(float v) {
#pragma unroll
  for (int off = 16; off > 0; off >>= 1) v = fmaxf(v, __shfl_xor(v, off, 64));
  return v;
}
__device__ __forceinline__ float gelu_exact(float x) {
  return 0.5f * x * (1.0f + erff(x * 0.70710678118654752f));
}
__device__ __forceinline__ float leaky02(float x) {
  return x >= 0.f ? x : 0.2f * x;
}

// ---------------- fused prep: castx | prepw | hist(8-replica, +rank) -----------
#define PREP_CAST 6250   // NN*FIN/4 / 256
#define PREP_W 169       // ceil(43168/256)
#define PREP_HIST 3125   // EE/256
__global__ __launch_bounds__(256) void k_prep(
    const float* __restrict__ x, const int* __restrict__ dst,
    const float* __restrict__ W0, const float* __restrict__ W1,
    const float* __restrict__ W2, const float* __restrict__ W3,
    const float* __restrict__ Q0, const float* __restrict__ Q1,
    const float* __restrict__ Q2, const float* __restrict__ Q3,
    const float* __restrict__ b0, const float* __restrict__ b1,
    const float* __restrict__ b2, const float* __restrict__ b3,
    ushort_t* __restrict__ xb, ushort_t* __restrict__ WtA,
    ushort_t* __restrict__ WtB, float* __restrict__ bcat,
    int* __restrict__ cntR, int* __restrict__ erank) {
  int b = blockIdx.x, t = threadIdx.x;
  if (b < PREP_CAST) {
    int i = b * 256 + t;
    if (i < NN * FIN / 4) {
      float4 v = ((const float4*)x)[i];
      ushort4 o;
      o.x = f2bf(v.x); o.y = f2bf(v.y); o.z = f2bf(v.z); o.w = f2bf(v.w);
      ((ushort4*)xb)[i] = o;
    }
  } else if (b < PREP_CAST + PREP_W) {
    int idx = (b - PREP_CAST) * 256 + t;
    if (idx < 32768) {
      int m = idx >> 13, r = idx & 8191, c = r >> 7, k = r & 127;
      const float* W = (m == 0) ? W0 : (m == 1) ? W1 : (m == 2) ? W2 : W3;
      WtA[idx] = f2bf(W[k * HID + c]);
    } else if (idx < 43008) {
      int j = idx - 32768;
      int c = j >> 6, k = j & 63;
      int mm = c / CL, cc = c % CL;
      const float* W = (mm == 0) ? Q0 : (mm == 1) ? Q1 : (mm == 2) ? Q2 : Q3;
      WtB[j] = f2bf(W[k * CL + cc]);
    } else if (idx < 43168) {
      int c = idx - 43008;
      int mm = c / CL, cc = c % CL;
      const float* bb = (mm == 0) ? b0 : (mm == 1) ? b1 : (mm == 2) ? b2 : b3;
      bcat[c] = bb[cc];
    }
  } else {
    int e = (b - PREP_CAST - PREP_W) * 256 + t;
    if (e < EE) {
      int r = e & (NREP - 1);
      erank[e] = atomicAdd(&cntR[(size_t)r * NN + dst[e]], 1);
    }
  }
}

// ---------------- MFMA GEMM A (+fused att scalars on m==2) ---------------------
__global__ __launch_bounds__(256) void k_gemmA(
    const ushort_t* __restrict__ xb, const ushort_t* __restrict__ WtA,
    const float* __restrict__ attS, const float* __restrict__ attD,
    ushort_t* __restrict__ Hb, float* __restrict__ a_s,
    float* __restrict__ a_d) {
  __shared__ __align__(16) ushort_t wlds[64 * 136];  // [c][k] padded +8
  const int t = threadIdx.x;
  const int m = blockIdx.y;
  for (int idx = t; idx < 64 * 16; idx += 256) {
    int c = idx >> 4, ch = idx & 15;
    *(uint4*)&wlds[c * 136 + ch * 8] =
        *(const uint4*)(WtA + m * 8192 + c * 128 + ch * 8);
  }
  __syncthreads();
  const int wv = t >> 6, l = t & 63;
  const int lr = l & 15, lg = l >> 4;
  const int rbase = blockIdx.x * 64 + wv * 16;
  int arow = rbase + lr;
  int arowc = arow < NN ? arow : NN - 1;
  const ushort_t* ap = xb + (size_t)arowc * 128 + lg * 8;
  f32x4 acc[4] = {};
#pragma unroll
  for (int ks = 0; ks < 4; ++ks) {
    s16x8 af = *(const s16x8*)(ap + ks * 32);
#pragma unroll
    for (int n = 0; n < 4; ++n) {
      s16x8 bf = *(const s16x8*)&wlds[(n * 16 + lr) * 136 + ks * 32 + lg * 8];
      acc[n] = __builtin_amdgcn_mfma_f32_16x16x32_bf16(af, bf, acc[n], 0, 0, 0);
    }
  }
#pragma unroll
  for (int n = 0; n < 4; ++n) {
#pragma unroll
    for (int j = 0; j < 4; ++j) {
      int orow = rbase + lg * 4 + j;
      if (orow < NN)
        Hb[(size_t)orow * 256 + m * 64 + n * 16 + lr] = f2bf(acc[n][j]);
    }
  }
  if (m == 2) {  // GAT block: a_s/a_d from fp32 acc. col = n*16+lr, row=lg*4+j
    float sat[4], dat[4];
#pragma unroll
    for (int n = 0; n < 4; ++n) {
      sat[n] = attS[n * 16 + lr];
      dat[n] = attD[n * 16 + lr];
    }
#pragma unroll
    for (int j = 0; j < 4; ++j) {
      float ps = 0.f, pd = 0.f;
#pragma unroll
      for (int n = 0; n < 4; ++n) {
        ps = fmaf(acc[n][j], sat[n], ps);
        pd = fmaf(acc[n][j], dat[n], pd);
      }
#pragma unroll
      for (int off = 1; off < 16; off <<= 1) {
        ps += __shfl_xor(ps, off, 64);
        pd += __shfl_xor(pd, off, 64);
      }
      int orow = rbase + lg * 4 + j;
      if (lr == 0 && orow < NN) { a_s[orow] = ps; a_d[orow] = pd; }
    }
  }
}

// ---------------- block sums of replica counts ---------------------------------
__global__ __launch_bounds__(SCB) void k_bsum(const int* __restrict__ cntR,
                                              int* __restrict__ bsum) {
  __shared__ int wsm[4];
  int i = blockIdx.x * SCB + threadIdx.x;
  int v = 0;
  if (i < NN) {
#pragma unroll
    for (int r = 0; r < NREP; ++r) v += cntR[(size_t)r * NN + i];
  }
  int s = wave_sum_i(v);
  int lane = threadIdx.x & 63, wv = threadIdx.x >> 6;
  if (lane == 0) wsm[wv] = s;
  __syncthreads();
  if (threadIdx.x == 0) bsum[blockIdx.x] = wsm[0] + wsm[1] + wsm[2] + wsm[3];
}

// ---------------- fused bscan+apply + replica-base computation -----------------
__global__ __launch_bounds__(SCB) void k_scanapply(
    const int* __restrict__ cntR, const int* __restrict__ bsum,
    int* __restrict__ cnt, int* __restrict__ offs, int* __restrict__ base8,
    float* __restrict__ dinv) {
  __shared__ int ts[SCB];
  __shared__ int wred[4];
  int b = blockIdx.x, t = threadIdx.x;
  int pv = (t < b) ? bsum[t] : 0;  // b<=195, t<b implies t<196=NBLK
  int ps = wave_sum_i(pv);
  int lane = t & 63, wv = t >> 6;
  if (lane == 0) wred[wv] = ps;
  int i = b * SCB + t;
  int cr[NREP];
  int v = 0;
  if (i < NN) {
#pragma unroll
    for (int r = 0; r < NREP; ++r) {
      cr[r] = cntR[(size_t)r * NN + i];
      v += cr[r];
    }
  }
  ts[t] = v;
  __syncthreads();
  int prefix = wred[0] + wred[1] + wred[2] + wred[3];
  for (int off = 1; off < SCB; off <<= 1) {
    int u = (t >= off) ? ts[t - off] : 0;
    __syncthreads();
    ts[t] += u;
    __syncthreads();
  }
  if (i < NN) {
    int ex = ts[t] - v + prefix;
    offs[i] = ex;
    cnt[i] = v;
    dinv[i] = rsqrtf((float)v + 1.0f);
    int run = ex;
#pragma unroll
    for (int r = 0; r < NREP; ++r) {
      base8[(size_t)i * NREP + r] = run;
      run += cr[r];
    }
  }
}

// ---------------- atomic-free scatter + per-edge scalar precompute -------------
__global__ __launch_bounds__(256) void k_scatter(
    const int* __restrict__ src, const int* __restrict__ dst,
    const int* __restrict__ erank, const int* __restrict__ base8,
    const float* __restrict__ a_s, const float* __restrict__ a_d,
    const float* __restrict__ dinv, int* __restrict__ srcidx,
    int* __restrict__ dsts, float2* __restrict__ edata) {
  int e = blockIdx.x * blockDim.x + threadIdx.x;
  if (e < EE) {
    int s = src[e], d = dst[e];
    int p = base8[(size_t)d * NREP + (e & (NREP - 1))] + erank[e];
    srcidx[p] = s;
    dsts[p] = d;
    float ex = __expf(leaky02(a_s[s] + a_d[d]));
    edata[p] = make_float2(dinv[s] * dinv[d], ex);
  }
}

// ---------------- fused GCN+SAGE+GAT aggregation + gelu ensemble ---------------
__global__ __launch_bounds__(256) void k_agg1(
    const int* __restrict__ srcidx, const int* __restrict__ offs,
    const int* __restrict__ cnt, const ushort_t* __restrict__ Hb,
    const float2* __restrict__ edata, const float* __restrict__ dinv,
    const float* __restrict__ a_s, const float* __restrict__ a_d,
    const float* __restrict__ b_gcn, const float* __restrict__ bl,
    const float* __restrict__ b_gat, const float* __restrict__ w,
    ushort_t* __restrict__ ensb) {
  int node = (blockIdx.x * blockDim.x + threadIdx.x) >> 6;
  int lane = threadIdx.x & 63;
  if (node >= NN) return;
  const int half = lane >> 5;
  const int fl = lane & 31;
  int beg = offs[node];
  int c = cnt[node];
  int end = beg + c;
  float ag0 = 0.f, ag1 = 0.f, as0 = 0.f, as1 = 0.f, aa0 = 0.f, aa1 = 0.f,
        dg = 0.f;
  int p = beg + half;
  for (; p + 6 < end; p += 8) {
    int sA = srcidx[p], sB = srcidx[p + 2], sC = srcidx[p + 4],
        sD = srcidx[p + 6];
    float2 eA = edata[p], eB = edata[p + 2], eC = edata[p + 4],
           eD = edata[p + 6];
    const uint_t* hA = (const uint_t*)(Hb + (size_t)sA * 256);
    const uint_t* hB = (const uint_t*)(Hb + (size_t)sB * 256);
    const uint_t* hC = (const uint_t*)(Hb + (size_t)sC * 256);
    const uint_t* hD = (const uint_t*)(Hb + (size_t)sD * 256);
    uint_t gA = hA[fl], qA = hA[32 + fl], tA = hA[64 + fl];
    uint_t gB = hB[fl], qB = hB[32 + fl], tB = hB[64 + fl];
    uint_t gC = hC[fl], qC = hC[32 + fl], tC = hC[64 + fl];
    uint_t gD = hD[fl], qD = hD[32 + fl], tD = hD[64 + fl];
    ag0 = fmaf(bflo(gA), eA.x, ag0); ag1 = fmaf(bfhi(gA), eA.x, ag1);
    ag0 = fmaf(bflo(gB), eB.x, ag0); ag1 = fmaf(bfhi(gB), eB.x, ag1);
    ag0 = fmaf(bflo(gC), eC.x, ag0); ag1 = fmaf(bfhi(gC), eC.x, ag1);
    ag0 = fmaf(bflo(gD), eD.x, ag0); ag1 = fmaf(bfhi(gD), eD.x, ag1);
    as0 += (bflo(qA) + bflo(qB)) + (bflo(qC) + bflo(qD));
    as1 += (bfhi(qA) + bfhi(qB)) + (bfhi(qC) + bfhi(qD));
    aa0 = fmaf(bflo(tA), eA.y, aa0); aa1 = fmaf(bfhi(tA), eA.y, aa1);
    aa0 = fmaf(bflo(tB), eB.y, aa0); aa1 = fmaf(bfhi(tB), eB.y, aa1);
    aa0 = fmaf(bflo(tC), eC.y, aa0); aa1 = fmaf(bfhi(tC), eC.y, aa1);
    aa0 = fmaf(bflo(tD), eD.y, aa0); aa1 = fmaf(bfhi(tD), eD.y, aa1);
    dg += (eA.y + eB.y) + (eC.y + eD.y);
  }
  for (; p < end; p += 2) {
    int sA = srcidx[p];
    float2 eA = edata[p];
    const uint_t* hA = (const uint_t*)(Hb + (size_t)sA * 256);
    uint_t gA = hA[fl], qA = hA[32 + fl], tA = hA[64 + fl];
    ag0 = fmaf(bflo(gA), eA.x, ag0); ag1 = fmaf(bfhi(gA), eA.x, ag1);
    as0 += bflo(qA);                 as1 += bfhi(qA);
    aa0 = fmaf(bflo(tA), eA.y, aa0); aa1 = fmaf(bfhi(tA), eA.y, aa1);
    dg += eA.y;
  }
  // fold halves
  ag0 += __shfl_xor(ag0, 32, 64); ag1 += __shfl_xor(ag1, 32, 64);
  as0 += __shfl_xor(as0, 32, 64); as1 += __shfl_xor(as1, 32, 64);
  aa0 += __shfl_xor(aa0, 32, 64); aa1 += __shfl_xor(aa1, 32, 64);
  dg += __shfl_xor(dg, 32, 64);
  // epilogue
  float dd = dinv[node];
  float exl = __expf(leaky02(a_s[node] + a_d[node]));
  const uint_t* hd = (const uint_t*)(Hb + (size_t)node * 256);
  uint_t hg = hd[fl], ht = hd[64 + fl], hr = hd[96 + fl];
  float2 bg = ((const float2*)b_gcn)[fl];
  float2 bs = ((const float2*)bl)[fl];
  float2 ba = ((const float2*)b_gat)[fl];
  float dd2 = dd * dd;
  float cinv = 1.0f / fmaxf((float)c, 1.0f);
  float gdi = 1.0f / (dg + exl + 1e-16f);
  float g0 = ag0 + dd2 * bflo(hg) + bg.x;
  float g1 = ag1 + dd2 * bfhi(hg) + bg.y;
  float s0 = as0 * cinv + bs.x + bflo(hr);
  float s1 = as1 * cinv + bs.y + bfhi(hr);
  float t0 = (aa0 + exl * bflo(ht)) * gdi + ba.x;
  float t1 = (aa1 + exl * bfhi(ht)) * gdi + ba.y;
  float w0 = w[0], w1 = w[1], w2 = w[2];
  float e0 = w0 * gelu_exact(g0) + w1 * gelu_exact(s0) + w2 * gelu_exact(t0);
  float e1 = w0 * gelu_exact(g1) + w1 * gelu_exact(s1) + w2 * gelu_exact(t1);
  if (half == 0) ((uint_t*)ensb)[(size_t)node * 32 + fl] = f2bf2(e0, e1);
}

// ---------------- MFMA GEMM B: QKVSb = bf16(ens @ [Wq|Wk|Wv|Wskip] + bias) -----
__global__ __launch_bounds__(256) void k_gemmB(
    const ushort_t* __restrict__ ensb, const ushort_t* __restrict__ WtB,
    const float* __restrict__ bcat, ushort_t* __restrict__ QKVSb) {
  __shared__ __align__(16) ushort_t wb[160 * 72];  // [c][k] padded +8
  __shared__ float bsh[160];
  const int t = threadIdx.x;
  for (int idx = t; idx < 160 * 8; idx += 256) {
    int c = idx >> 3, ch = idx & 7;
    *(uint4*)&wb[c * 72 + ch * 8] = *(const uint4*)(WtB + c * 64 + ch * 8);
  }
  if (t < 160) bsh[t] = bcat[t];
  __syncthreads();
  const int wv = t >> 6, l = t & 63;
  const int lr = l & 15, lg = l >> 4;
  const int rbase = blockIdx.x * 64 + wv * 16;
  int arow = rbase + lr;
  int arowc = arow < NN ? arow : NN - 1;
  const ushort_t* ap = ensb + (size_t)arowc * 64 + lg * 8;
  f32x4 acc[10] = {};
#pragma unroll
  for (int ks = 0; ks < 2; ++ks) {
    s16x8 af = *(const s16x8*)(ap + ks * 32);
#pragma unroll
    for (int n = 0; n < 10; ++n) {
      s16x8 bf = *(const s16x8*)&wb[(n * 16 + lr) * 72 + ks * 32 + lg * 8];
      acc[n] = __builtin_amdgcn_mfma_f32_16x16x32_bf16(af, bf, acc[n], 0, 0, 0);
    }
  }
#pragma unroll
  for (int n = 0; n < 10; ++n) {
    int col = n * 16 + lr;
#pragma unroll
    for (int j = 0; j < 4; ++j) {
      int orow = rbase + lg * 4 + j;
      if (orow < NN)
        QKVSb[(size_t)orow * 160 + col] = f2bf(acc[n][j] + bsh[col]);
    }
  }
}

// ---------------- edge-parallel transformer scores (8 lanes/edge) --------------
__global__ __launch_bounds__(256) void k_score(
    const int* __restrict__ srcidx, const int* __restrict__ dsts,
    const ushort_t* __restrict__ QKVSb, float* __restrict__ escore) {
  int p = (blockIdx.x * 256 + threadIdx.x) >> 3;
  int l = threadIdx.x & 7;
  if (p >= EE) return;
  int s = srcidx[p], d = dsts[p];
  float part = 0.f;
  if (l < 5) {
    const uint4 qv = *(const uint4*)(QKVSb + (size_t)d * 160 + l * 8);
    const uint4 kv = *(const uint4*)(QKVSb + (size_t)s * 160 + 40 + l * 8);
    part = bflo(qv.x) * bflo(kv.x);
    part = fmaf(bfhi(qv.x), bfhi(kv.x), part);
    part = fmaf(bflo(qv.y), bflo(kv.y), part);
    part = fmaf(bfhi(qv.y), bfhi(kv.y), part);
    part = fmaf(bflo(qv.z), bflo(kv.z), part);
    part = fmaf(bfhi(qv.z), bfhi(kv.z), part);
    part = fmaf(bflo(qv.w), bflo(kv.w), part);
    part = fmaf(bfhi(qv.w), bfhi(kv.w), part);
  }
  part += __shfl_xor(part, 1, 64);
  part += __shfl_xor(part, 2, 64);
  part += __shfl_xor(part, 4, 64);
  if (l == 0) escore[p] = __expf(part * 0.15811388300841897f);
}

// ---------------- transformer aggregation + log_softmax ------------------------
__global__ __launch_bounds__(256) void k_agg2(
    const int* __restrict__ srcidx, const int* __restrict__ offs,
    const int* __restrict__ cnt, const ushort_t* __restrict__ QKVSb,
    const float* __restrict__ escore, float* __restrict__ out) {
  int node = (blockIdx.x * blockDim.x + threadIdx.x) >> 6;
  int lane = threadIdx.x & 63;
  if (node >= NN) return;
  const int half = lane >> 5;
  const int fl = lane & 31;   // feature-pair index (feats 2fl, 2fl+1 of 40)
  const bool valid = fl < 20;
  int beg = offs[node];
  int end = beg + cnt[node];
  float den = 0.f, av0 = 0.f, av1 = 0.f;
  int p = beg + half;
  for (; p + 6 < end; p += 8) {
    int sA = srcidx[p], sB = srcidx[p + 2], sC = srcidx[p + 4],
        sD = srcidx[p + 6];
    float eA = escore[p], eB = escore[p + 2], eC = escore[p + 4],
          eD = escore[p + 6];
    uint_t vA = valid ? ((const uint_t*)(QKVSb + (size_t)sA * 160))[40 + fl] : 0u;
    uint_t vB = valid ? ((const uint_t*)(QKVSb + (size_t)sB * 160))[40 + fl] : 0u;
    uint_t vC = valid ? ((const uint_t*)(QKVSb + (size_t)sC * 160))[40 + fl] : 0u;
    uint_t vD = valid ? ((const uint_t*)(QKVSb + (size_t)sD * 160))[40 + fl] : 0u;
    av0 = fmaf(eA, bflo(vA), av0); av1 = fmaf(eA, bfhi(vA), av1);
    av0 = fmaf(eB, bflo(vB), av0); av1 = fmaf(eB, bfhi(vB), av1);
    av0 = fmaf(eC, bflo(vC), av0); av1 = fmaf(eC, bfhi(vC), av1);
    av0 = fmaf(eD, bflo(vD), av0); av1 = fmaf(eD, bfhi(vD), av1);
    den += (eA + eB) + (eC + eD);
  }
  for (; p < end; p += 2) {
    int sA = srcidx[p];
    float eA = escore[p];
    uint_t vA = valid ? ((const uint_t*)(QKVSb + (size_t)sA * 160))[40 + fl] : 0u;
    av0 = fmaf(eA, bflo(vA), av0); av1 = fmaf(eA, bfhi(vA), av1);
    den += eA;
  }
  // fold halves
  av0 += __shfl_xor(av0, 32, 64);
  av1 += __shfl_xor(av1, 32, 64);
  den += __shfl_xor(den, 32, 64);
  const uint_t* rd = (const uint_t*)(QKVSb + (size_t)node * 160);
  uint_t sk = valid ? rd[60 + fl] : 0u;
  float di = 1.0f / (den + 1e-16f);
  float o0 = valid ? av0 * di + bflo(sk) : -3.0e38f;
  float o1 = valid ? av1 * di + bfhi(sk) : -3.0e38f;
  float m = half_max(fmaxf(o0, o1));
  float eo = valid ? __expf(o0 - m) + __expf(o1 - m) : 0.f;
  float ls = logf(half_sum(eo));
  if (valid && half == 0) {
    float2 r = make_float2(o0 - m - ls, o1 - m - ls);
    ((float2*)out)[(size_t)node * 20 + fl] = r;
  }
}

extern "C" void kernel_launch(void* const* d_in, const int* in_sizes, int n_in,
                              void* d_out, int out_size, void* d_ws,
                              size_t ws_size, hipStream_t stream) {
  const float* x     = (const float*)d_in[0];
  const int*   ei    = (const int*)d_in[1];
  const float* w     = (const float*)d_in[2];
  const float* W_gcn = (const float*)d_in[3];
  const float* b_gcn = (const float*)d_in[4];
  const float* Wl    = (const float*)d_in[5];
  const float* bl    = (const float*)d_in[6];
  const float* Wr    = (const float*)d_in[7];
  const float* W_gat = (const float*)d_in[8];
  const float* att_s = (const float*)d_in[9];
  const float* att_d = (const float*)d_in[10];
  const float* b_gat = (const float*)d_in[11];
  const float* Wq    = (const float*)d_in[12];
  const float* bq    = (const float*)d_in[13];
  const float* Wk    = (const float*)d_in[14];
  const float* bk    = (const float*)d_in[15];
  const float* Wv    = (const float*)d_in[16];
  const float* bv    = (const float*)d_in[17];
  const float* Wsk   = (const float*)d_in[18];
  const float* bsk   = (const float*)d_in[19];
  float* out = (float*)d_out;
  float* ws  = (float*)d_ws;

  const int* src = ei;
  const int* dst = ei + EE;

  // workspace layout (float-unit offsets)
  ushort_t* Hb     = (ushort_t*)ws;                       // 128N fl
  ushort_t* ensb   = (ushort_t*)(ws + (size_t)128 * NN);  // 32N fl
  float*    a_s    = ws + (size_t)160 * NN;               // N
  float*    a_d    = ws + (size_t)161 * NN;               // N
  float*    dinv   = ws + (size_t)162 * NN;               // N
  ushort_t* qkvsb  = (ushort_t*)(ws + (size_t)163 * NN);  // 80N fl
  ushort_t* xb     = (ushort_t*)(ws + (size_t)243 * NN);  // 64N fl
  ushort_t* WtA    = (ushort_t*)(ws + (size_t)307 * NN);  // 16384 fl
  ushort_t* WtB    = (ushort_t*)(ws + (size_t)307 * NN + 16384);  // 5120 fl
  float*    bcat   = ws + (size_t)307 * NN + 21504;       // 160 fl
  float*    escore = ws + (size_t)307 * NN + 21664;       // EE fl
  float2*   edata  = (float2*)(ws + (size_t)307 * NN + 21664 + EE);  // 2EE fl
  int*      ibase  = (int*)(ws + (size_t)307 * NN + 21664 + 3 * (size_t)EE);
  int*      cnt    = ibase;                               // N
  int*      offs   = ibase + NN;                          // N
  int*      srcidx = ibase + 2 * NN;                      // EE
  int*      dsts   = ibase + 2 * NN + EE;                 // EE
  int*      erank  = ibase + 2 * NN + 2 * EE;             // EE
  int*      bsum   = ibase + 2 * NN + 3 * EE;             // NBLK
  int*      cntR   = ibase + 2 * NN + 3 * EE + 256;       // 8N
  int*      base8  = cntR + (size_t)NREP * NN;            // 8N

  hipMemsetAsync(cntR, 0, (size_t)NREP * NN * sizeof(int), stream);

  k_prep<<<PREP_CAST + PREP_W + PREP_HIST, 256, 0, stream>>>(
      x, dst, W_gcn, Wl, W_gat, Wr, Wq, Wk, Wv, Wsk, bq, bk, bv, bsk, xb, WtA,
      WtB, bcat, cntR, erank);

  dim3 gA((NN + 63) / 64, 4);
  k_gemmA<<<gA, 256, 0, stream>>>(xb, WtA, att_s, att_d, Hb, a_s, a_d);
  k_bsum<<<NBLK, SCB, 0, stream>>>(cntR, bsum);
  k_scanapply<<<NBLK, SCB, 0, stream>>>(cntR, bsum, cnt, offs, base8, dinv);
  k_scatter<<<(EE + 255) / 256, 256, 0, stream>>>(src, dst, erank, base8, a_s,
                                                  a_d, dinv, srcidx, dsts,
                                                  edata);
  k_agg1<<<(NN + 3) / 4, 256, 0, stream>>>(srcidx, offs, cnt, Hb, edata, dinv,
                                           a_s, a_d, b_gcn, bl, b_gat, w, ensb);
  k_gemmB<<<(NN + 63) / 64, 256, 0, stream>>>(ensb, WtB, bcat, qkvsb);
  k_score<<<(EE * 8 + 255) / 256, 256, 0, stream>>>(srcidx, dsts, qkvsb,
                                                    escore);
  k_agg2<<<(NN + 3) / 4, 256, 0, stream>>>(srcidx, offs, cnt, qkvsb, escore,
                                           out);
}

// Round 11
// 219.684 us; speedup vs baseline: 1.0017x; 1.0017x over previous
//
#include <hip/hip_runtime.h>
#include <math.h>

#define NN 50000
#define EE 800000
#define FIN 128
#define HID 64
#define CL 40
#define SCB 256
#define NBLK ((NN + SCB - 1) / SCB)  // 196
#define NREP 8

typedef unsigned short ushort_t;
typedef unsigned int uint_t;
typedef float f32x4 __attribute__((ext_vector_type(4)));
typedef short s16x8 __attribute__((ext_vector_type(8)));

__device__ __forceinline__ ushort_t f2bf(float f) {
  uint_t u = __float_as_uint(f);
  u = (u + 0x7FFFu + ((u >> 16) & 1u)) >> 16;  // RNE
  return (ushort_t)u;
}
__device__ __forceinline__ uint_t f2bf2(float lo, float hi) {
  return (uint_t)f2bf(lo) | ((uint_t)f2bf(hi) << 16);
}
__device__ __forceinline__ float bf2f(ushort_t s) {
  return __uint_as_float(((uint_t)s) << 16);
}
__device__ __forceinline__ float bflo(uint_t u) {
  return __uint_as_float(u << 16);
}
__device__ __forceinline__ float bfhi(uint_t u) {
  return __uint_as_float(u & 0xFFFF0000u);
}

__device__ __forceinline__ int wave_sum_i(int v) {
#pragma unroll
  for (int off = 32; off > 0; off >>= 1) v += __shfl_xor(v, off, 64);
  return v;
}
__device__ __forceinline__ float half_sum(float v) {  // within 32-lane half
#pragma unroll
  for (int off = 16; off > 0; off >>= 1) v += __shfl_xor(v, off, 64);
  return v;
}
__device__ __forceinline__ float half_max(float v) {
#pragma unroll
  for (int off = 16; off > 0; off >>= 1) v = fmaxf(v, __shfl_xor(v, off, 64));
  return v;
}
__device__ __forceinline__ float gelu_exact(float x) {
  return 0.5f * x * (1.0f + erff(x * 0.70710678118654752f));
}
__device__ __forceinline__ float leaky02(float x) {
  return x >= 0.f ? x : 0.2f * x;
}

// ---------------- fused prep: castx | prepw | hist(8-replica, +rank) -----------
#define PREP_CAST 6250   // NN*FIN/4 / 256
#define PREP_W 169       // ceil(43168/256)
#define PREP_HIST 3125   // EE/256
__global__ __launch_bounds__(256) void k_prep(
    const float* __restrict__ x, const int* __restrict__ dst,
    const float* __restrict__ W0, const float* __restrict__ W1,
    const float* __restrict__ W2, const float* __restrict__ W3,
    const float* __restrict__ Q0, const float* __restrict__ Q1,
    const float* __restrict__ Q2, const float* __restrict__ Q3,
    const float* __restrict__ b0, const float* __restrict__ b1,
    const float* __restrict__ b2, const float* __restrict__ b3,
    ushort_t* __restrict__ xb, ushort_t* __restrict__ WtA,
    ushort_t* __restrict__ WtB, float* __restrict__ bcat,
    int* __restrict__ cntR, int* __restrict__ erank) {
  int b = blockIdx.x, t = threadIdx.x;
  if (b < PREP_CAST) {
    int i = b * 256 + t;
    if (i < NN * FIN / 4) {
      float4 v = ((const float4*)x)[i];
      ushort4 o;
      o.x = f2bf(v.x); o.y = f2bf(v.y); o.z = f2bf(v.z); o.w = f2bf(v.w);
      ((ushort4*)xb)[i] = o;
    }
  } else if (b < PREP_CAST + PREP_W) {
    int idx = (b - PREP_CAST) * 256 + t;
    if (idx < 32768) {
      int m = idx >> 13, r = idx & 8191, c = r >> 7, k = r & 127;
      const float* W = (m == 0) ? W0 : (m == 1) ? W1 : (m == 2) ? W2 : W3;
      WtA[idx] = f2bf(W[k * HID + c]);
    } else if (idx < 43008) {
      int j = idx - 32768;
      int c = j >> 6, k = j & 63;
      int mm = c / CL, cc = c % CL;
      const float* W = (mm == 0) ? Q0 : (mm == 1) ? Q1 : (mm == 2) ? Q2 : Q3;
      WtB[j] = f2bf(W[k * CL + cc]);
    } else if (idx < 43168) {
      int c = idx - 43008;
      int mm = c / CL, cc = c % CL;
      const float* bb = (mm == 0) ? b0 : (mm == 1) ? b1 : (mm == 2) ? b2 : b3;
      bcat[c] = bb[cc];
    }
  } else {
    int e = (b - PREP_CAST - PREP_W) * 256 + t;
    if (e < EE) {
      int r = e & (NREP - 1);
      erank[e] = atomicAdd(&cntR[(size_t)r * NN + dst[e]], 1);
    }
  }
}

// ---------------- MFMA GEMM A (+fused att scalars on m==2) ---------------------
__global__ __launch_bounds__(256) void k_gemmA(
    const ushort_t* __restrict__ xb, const ushort_t* __restrict__ WtA,
    const float* __restrict__ attS, const float* __restrict__ attD,
    ushort_t* __restrict__ Hb, float* __restrict__ a_s,
    float* __restrict__ a_d) {
  __shared__ __align__(16) ushort_t wlds[64 * 136];  // [c][k] padded +8
  const int t = threadIdx.x;
  const int m = blockIdx.y;
  for (int idx = t; idx < 64 * 16; idx += 256) {
    int c = idx >> 4, ch = idx & 15;
    *(uint4*)&wlds[c * 136 + ch * 8] =
        *(const uint4*)(WtA + m * 8192 + c * 128 + ch * 8);
  }
  __syncthreads();
  const int wv = t >> 6, l = t & 63;
  const int lr = l & 15, lg = l >> 4;
  const int rbase = blockIdx.x * 64 + wv * 16;
  int arow = rbase + lr;
  int arowc = arow < NN ? arow : NN - 1;
  const ushort_t* ap = xb + (size_t)arowc * 128 + lg * 8;
  f32x4 acc[4] = {};
#pragma unroll
  for (int ks = 0; ks < 4; ++ks) {
    s16x8 af = *(const s16x8*)(ap + ks * 32);
#pragma unroll
    for (int n = 0; n < 4; ++n) {
      s16x8 bf = *(const s16x8*)&wlds[(n * 16 + lr) * 136 + ks * 32 + lg * 8];
      acc[n] = __builtin_amdgcn_mfma_f32_16x16x32_bf16(af, bf, acc[n], 0, 0, 0);
    }
  }
#pragma unroll
  for (int n = 0; n < 4; ++n) {
#pragma unroll
    for (int j = 0; j < 4; ++j) {
      int orow = rbase + lg * 4 + j;
      if (orow < NN)
        Hb[(size_t)orow * 256 + m * 64 + n * 16 + lr] = f2bf(acc[n][j]);
    }
  }
  if (m == 2) {  // GAT block: a_s/a_d from fp32 acc. col = n*16+lr, row=lg*4+j
    float sat[4], dat[4];
#pragma unroll
    for (int n = 0; n < 4; ++n) {
      sat[n] = attS[n * 16 + lr];
      dat[n] = attD[n * 16 + lr];
    }
#pragma unroll
    for (int j = 0; j < 4; ++j) {
      float ps = 0.f, pd = 0.f;
#pragma unroll
      for (int n = 0; n < 4; ++n) {
        ps = fmaf(acc[n][j], sat[n], ps);
        pd = fmaf(acc[n][j], dat[n], pd);
      }
#pragma unroll
      for (int off = 1; off < 16; off <<= 1) {
        ps += __shfl_xor(ps, off, 64);
        pd += __shfl_xor(pd, off, 64);
      }
      int orow = rbase + lg * 4 + j;
      if (lr == 0 && orow < NN) { a_s[orow] = ps; a_d[orow] = pd; }
    }
  }
}

// ---------------- block sums of replica counts ---------------------------------
__global__ __launch_bounds__(SCB) void k_bsum(const int* __restrict__ cntR,
                                              int* __restrict__ bsum) {
  __shared__ int wsm[4];
  int i = blockIdx.x * SCB + threadIdx.x;
  int v = 0;
  if (i < NN) {
#pragma unroll
    for (int r = 0; r < NREP; ++r) v += cntR[(size_t)r * NN + i];
  }
  int s = wave_sum_i(v);
  int lane = threadIdx.x & 63, wv = threadIdx.x >> 6;
  if (lane == 0) wsm[wv] = s;
  __syncthreads();
  if (threadIdx.x == 0) bsum[blockIdx.x] = wsm[0] + wsm[1] + wsm[2] + wsm[3];
}

// ---------------- fused bscan+apply + replica-base computation -----------------
__global__ __launch_bounds__(SCB) void k_scanapply(
    const int* __restrict__ cntR, const int* __restrict__ bsum,
    int* __restrict__ cnt, int* __restrict__ offs, int* __restrict__ base8,
    float* __restrict__ dinv) {
  __shared__ int ts[SCB];
  __shared__ int wred[4];
  int b = blockIdx.x, t = threadIdx.x;
  int pv = (t < b) ? bsum[t] : 0;  // b<=195, t<b implies t<196=NBLK
  int ps = wave_sum_i(pv);
  int lane = t & 63, wv = t >> 6;
  if (lane == 0) wred[wv] = ps;
  int i = b * SCB + t;
  int cr[NREP];
  int v = 0;
  if (i < NN) {
#pragma unroll
    for (int r = 0; r < NREP; ++r) {
      cr[r] = cntR[(size_t)r * NN + i];
      v += cr[r];
    }
  }
  ts[t] = v;
  __syncthreads();
  int prefix = wred[0] + wred[1] + wred[2] + wred[3];
  for (int off = 1; off < SCB; off <<= 1) {
    int u = (t >= off) ? ts[t - off] : 0;
    __syncthreads();
    ts[t] += u;
    __syncthreads();
  }
  if (i < NN) {
    int ex = ts[t] - v + prefix;
    offs[i] = ex;
    cnt[i] = v;
    dinv[i] = rsqrtf((float)v + 1.0f);
    int run = ex;
#pragma unroll
    for (int r = 0; r < NREP; ++r) {
      base8[(size_t)i * NREP + r] = run;
      run += cr[r];
    }
  }
}

// ---------------- scatter pass 1: inverse permutation only (4B/edge) -----------
__global__ __launch_bounds__(256) void k_sc1(const int* __restrict__ dst,
                                             const int* __restrict__ erank,
                                             const int* __restrict__ base8,
                                             int* __restrict__ esorted) {
  int e = blockIdx.x * blockDim.x + threadIdx.x;
  if (e < EE) {
    int d = dst[e];
    esorted[base8[(size_t)d * NREP + (e & (NREP - 1))] + erank[e]] = e;
  }
}

// ---------------- scatter pass 2: p-coalesced fill of sorted arrays ------------
__global__ __launch_bounds__(256) void k_sc2(
    const int* __restrict__ esorted, const int* __restrict__ src,
    const int* __restrict__ dst, const float* __restrict__ a_s,
    const float* __restrict__ a_d, const float* __restrict__ dinv,
    int* __restrict__ srcidx, int* __restrict__ dsts,
    float2* __restrict__ edata) {
  int p = blockIdx.x * blockDim.x + threadIdx.x;
  if (p < EE) {
    int e = esorted[p];
    int s = src[e], d = dst[e];
    srcidx[p] = s;
    dsts[p] = d;
    float ex = __expf(leaky02(a_s[s] + a_d[d]));
    edata[p] = make_float2(dinv[s] * dinv[d], ex);
  }
}

// ---------------- fused GCN+SAGE+GAT aggregation + gelu ensemble ---------------
__global__ __launch_bounds__(256) void k_agg1(
    const int* __restrict__ srcidx, const int* __restrict__ offs,
    const int* __restrict__ cnt, const ushort_t* __restrict__ Hb,
    const float2* __restrict__ edata, const float* __restrict__ dinv,
    const float* __restrict__ a_s, const float* __restrict__ a_d,
    const float* __restrict__ b_gcn, const float* __restrict__ bl,
    const float* __restrict__ b_gat, const float* __restrict__ w,
    ushort_t* __restrict__ ensb) {
  int node = (blockIdx.x * blockDim.x + threadIdx.x) >> 6;
  int lane = threadIdx.x & 63;
  if (node >= NN) return;
  const int half = lane >> 5;
  const int fl = lane & 31;
  int beg = offs[node];
  int c = cnt[node];
  int end = beg + c;
  float ag0 = 0.f, ag1 = 0.f, as0 = 0.f, as1 = 0.f, aa0 = 0.f, aa1 = 0.f,
        dg = 0.f;
  int p = beg + half;
  for (; p + 6 < end; p += 8) {
    int sA = srcidx[p], sB = srcidx[p + 2], sC = srcidx[p + 4],
        sD = srcidx[p + 6];
    float2 eA = edata[p], eB = edata[p + 2], eC = edata[p + 4],
           eD = edata[p + 6];
    const uint_t* hA = (const uint_t*)(Hb + (size_t)sA * 256);
    const uint_t* hB = (const uint_t*)(Hb + (size_t)sB * 256);
    const uint_t* hC = (const uint_t*)(Hb + (size_t)sC * 256);
    const uint_t* hD = (const uint_t*)(Hb + (size_t)sD * 256);
    uint_t gA = hA[fl], qA = hA[32 + fl], tA = hA[64 + fl];
    uint_t gB = hB[fl], qB = hB[32 + fl], tB = hB[64 + fl];
    uint_t gC = hC[fl], qC = hC[32 + fl], tC = hC[64 + fl];
    uint_t gD = hD[fl], qD = hD[32 + fl], tD = hD[64 + fl];
    ag0 = fmaf(bflo(gA), eA.x, ag0); ag1 = fmaf(bfhi(gA), eA.x, ag1);
    ag0 = fmaf(bflo(gB), eB.x, ag0); ag1 = fmaf(bfhi(gB), eB.x, ag1);
    ag0 = fmaf(bflo(gC), eC.x, ag0); ag1 = fmaf(bfhi(gC), eC.x, ag1);
    ag0 = fmaf(bflo(gD), eD.x, ag0); ag1 = fmaf(bfhi(gD), eD.x, ag1);
    as0 += (bflo(qA) + bflo(qB)) + (bflo(qC) + bflo(qD));
    as1 += (bfhi(qA) + bfhi(qB)) + (bfhi(qC) + bfhi(qD));
    aa0 = fmaf(bflo(tA), eA.y, aa0); aa1 = fmaf(bfhi(tA), eA.y, aa1);
    aa0 = fmaf(bflo(tB), eB.y, aa0); aa1 = fmaf(bfhi(tB), eB.y, aa1);
    aa0 = fmaf(bflo(tC), eC.y, aa0); aa1 = fmaf(bfhi(tC), eC.y, aa1);
    aa0 = fmaf(bflo(tD), eD.y, aa0); aa1 = fmaf(bfhi(tD), eD.y, aa1);
    dg += (eA.y + eB.y) + (eC.y + eD.y);
  }
  for (; p < end; p += 2) {
    int sA = srcidx[p];
    float2 eA = edata[p];
    const uint_t* hA = (const uint_t*)(Hb + (size_t)sA * 256);
    uint_t gA = hA[fl], qA = hA[32 + fl], tA = hA[64 + fl];
    ag0 = fmaf(bflo(gA), eA.x, ag0); ag1 = fmaf(bfhi(gA), eA.x, ag1);
    as0 += bflo(qA);                 as1 += bfhi(qA);
    aa0 = fmaf(bflo(tA), eA.y, aa0); aa1 = fmaf(bfhi(tA), eA.y, aa1);
    dg += eA.y;
  }
  // fold halves
  ag0 += __shfl_xor(ag0, 32, 64); ag1 += __shfl_xor(ag1, 32, 64);
  as0 += __shfl_xor(as0, 32, 64); as1 += __shfl_xor(as1, 32, 64);
  aa0 += __shfl_xor(aa0, 32, 64); aa1 += __shfl_xor(aa1, 32, 64);
  dg += __shfl_xor(dg, 32, 64);
  // epilogue
  float dd = dinv[node];
  float exl = __expf(leaky02(a_s[node] + a_d[node]));
  const uint_t* hd = (const uint_t*)(Hb + (size_t)node * 256);
  uint_t hg = hd[fl], ht = hd[64 + fl], hr = hd[96 + fl];
  float2 bg = ((const float2*)b_gcn)[fl];
  float2 bs = ((const float2*)bl)[fl];
  float2 ba = ((const float2*)b_gat)[fl];
  float dd2 = dd * dd;
  float cinv = 1.0f / fmaxf((float)c, 1.0f);
  float gdi = 1.0f / (dg + exl + 1e-16f);
  float g0 = ag0 + dd2 * bflo(hg) + bg.x;
  float g1 = ag1 + dd2 * bfhi(hg) + bg.y;
  float s0 = as0 * cinv + bs.x + bflo(hr);
  float s1 = as1 * cinv + bs.y + bfhi(hr);
  float t0 = (aa0 + exl * bflo(ht)) * gdi + ba.x;
  float t1 = (aa1 + exl * bfhi(ht)) * gdi + ba.y;
  float w0 = w[0], w1 = w[1], w2 = w[2];
  float e0 = w0 * gelu_exact(g0) + w1 * gelu_exact(s0) + w2 * gelu_exact(t0);
  float e1 = w0 * gelu_exact(g1) + w1 * gelu_exact(s1) + w2 * gelu_exact(t1);
  if (half == 0) ((uint_t*)ensb)[(size_t)node * 32 + fl] = f2bf2(e0, e1);
}

// ---------------- MFMA GEMM B: QKVSb = bf16(ens @ [Wq|Wk|Wv|Wskip] + bias) -----
__global__ __launch_bounds__(256) void k_gemmB(
    const ushort_t* __restrict__ ensb, const ushort_t* __restrict__ WtB,
    const float* __restrict__ bcat, ushort_t* __restrict__ QKVSb) {
  __shared__ __align__(16) ushort_t wb[160 * 72];  // [c][k] padded +8
  __shared__ float bsh[160];
  const int t = threadIdx.x;
  for (int idx = t; idx < 160 * 8; idx += 256) {
    int c = idx >> 3, ch = idx & 7;
    *(uint4*)&wb[c * 72 + ch * 8] = *(const uint4*)(WtB + c * 64 + ch * 8);
  }
  if (t < 160) bsh[t] = bcat[t];
  __syncthreads();
  const int wv = t >> 6, l = t & 63;
  const int lr = l & 15, lg = l >> 4;
  const int rbase = blockIdx.x * 64 + wv * 16;
  int arow = rbase + lr;
  int arowc = arow < NN ? arow : NN - 1;
  const ushort_t* ap = ensb + (size_t)arowc * 64 + lg * 8;
  f32x4 acc[10] = {};
#pragma unroll
  for (int ks = 0; ks < 2; ++ks) {
    s16x8 af = *(const s16x8*)(ap + ks * 32);
#pragma unroll
    for (int n = 0; n < 10; ++n) {
      s16x8 bf = *(const s16x8*)&wb[(n * 16 + lr) * 72 + ks * 32 + lg * 8];
      acc[n] = __builtin_amdgcn_mfma_f32_16x16x32_bf16(af, bf, acc[n], 0, 0, 0);
    }
  }
#pragma unroll
  for (int n = 0; n < 10; ++n) {
    int col = n * 16 + lr;
#pragma unroll
    for (int j = 0; j < 4; ++j) {
      int orow = rbase + lg * 4 + j;
      if (orow < NN)
        QKVSb[(size_t)orow * 160 + col] = f2bf(acc[n][j] + bsh[col]);
    }
  }
}

// ---------------- edge-parallel transformer scores (8 lanes/edge) --------------
__global__ __launch_bounds__(256) void k_score(
    const int* __restrict__ srcidx, const int* __restrict__ dsts,
    const ushort_t* __restrict__ QKVSb, float* __restrict__ escore) {
  int p = (blockIdx.x * 256 + threadIdx.x) >> 3;
  int l = threadIdx.x & 7;
  if (p >= EE) return;
  int s = srcidx[p], d = dsts[p];
  float part = 0.f;
  if (l < 5) {
    const uint4 qv = *(const uint4*)(QKVSb + (size_t)d * 160 + l * 8);
    const uint4 kv = *(const uint4*)(QKVSb + (size_t)s * 160 + 40 + l * 8);
    part = bflo(qv.x) * bflo(kv.x);
    part = fmaf(bfhi(qv.x), bfhi(kv.x), part);
    part = fmaf(bflo(qv.y), bflo(kv.y), part);
    part = fmaf(bfhi(qv.y), bfhi(kv.y), part);
    part = fmaf(bflo(qv.z), bflo(kv.z), part);
    part = fmaf(bfhi(qv.z), bfhi(kv.z), part);
    part = fmaf(bflo(qv.w), bflo(kv.w), part);
    part = fmaf(bfhi(qv.w), bfhi(kv.w), part);
  }
  part += __shfl_xor(part, 1, 64);
  part += __shfl_xor(part, 2, 64);
  part += __shfl_xor(part, 4, 64);
  if (l == 0) escore[p] = __expf(part * 0.15811388300841897f);
}

// ---------------- transformer aggregation + log_softmax ------------------------
__global__ __launch_bounds__(256) void k_agg2(
    const int* __restrict__ srcidx, const int* __restrict__ offs,
    const int* __restrict__ cnt, const ushort_t* __restrict__ QKVSb,
    const float* __restrict__ escore, float* __restrict__ out) {
  int node = (blockIdx.x * blockDim.x + threadIdx.x) >> 6;
  int lane = threadIdx.x & 63;
  if (node >= NN) return;
  const int half = lane >> 5;
  const int fl = lane & 31;   // feature-pair index (feats 2fl, 2fl+1 of 40)
  const bool valid = fl < 20;
  int beg = offs[node];
  int end = beg + cnt[node];
  float den = 0.f, av0 = 0.f, av1 = 0.f;
  int p = beg + half;
  for (; p + 6 < end; p += 8) {
    int sA = srcidx[p], sB = srcidx[p + 2], sC = srcidx[p + 4],
        sD = srcidx[p + 6];
    float eA = escore[p], eB = escore[p + 2], eC = escore[p + 4],
          eD = escore[p + 6];
    uint_t vA = valid ? ((const uint_t*)(QKVSb + (size_t)sA * 160))[40 + fl] : 0u;
    uint_t vB = valid ? ((const uint_t*)(QKVSb + (size_t)sB * 160))[40 + fl] : 0u;
    uint_t vC = valid ? ((const uint_t*)(QKVSb + (size_t)sC * 160))[40 + fl] : 0u;
    uint_t vD = valid ? ((const uint_t*)(QKVSb + (size_t)sD * 160))[40 + fl] : 0u;
    av0 = fmaf(eA, bflo(vA), av0); av1 = fmaf(eA, bfhi(vA), av1);
    av0 = fmaf(eB, bflo(vB), av0); av1 = fmaf(eB, bfhi(vB), av1);
    av0 = fmaf(eC, bflo(vC), av0); av1 = fmaf(eC, bfhi(vC), av1);
    av0 = fmaf(eD, bflo(vD), av0); av1 = fmaf(eD, bfhi(vD), av1);
    den += (eA + eB) + (eC + eD);
  }
  for (; p < end; p += 2) {
    int sA = srcidx[p];
    float eA = escore[p];
    uint_t vA = valid ? ((const uint_t*)(QKVSb + (size_t)sA * 160))[40 + fl] : 0u;
    av0 = fmaf(eA, bflo(vA), av0); av1 = fmaf(eA, bfhi(vA), av1);
    den += eA;
  }
  // fold halves
  av0 += __shfl_xor(av0, 32, 64);
  av1 += __shfl_xor(av1, 32, 64);
  den += __shfl_xor(den, 32, 64);
  const uint_t* rd = (const uint_t*)(QKVSb + (size_t)node * 160);
  uint_t sk = valid ? rd[60 + fl] : 0u;
  float di = 1.0f / (den + 1e-16f);
  float o0 = valid ? av0 * di + bflo(sk) : -3.0e38f;
  float o1 = valid ? av1 * di + bfhi(sk) : -3.0e38f;
  float m = half_max(fmaxf(o0, o1));
  float eo = valid ? __expf(o0 - m) + __expf(o1 - m) : 0.f;
  float ls = logf(half_sum(eo));
  if (valid && half == 0) {
    float2 r = make_float2(o0 - m - ls, o1 - m - ls);
    ((float2*)out)[(size_t)node * 20 + fl] = r;
  }
}

extern "C" void kernel_launch(void* const* d_in, const int* in_sizes, int n_in,
                              void* d_out, int out_size, void* d_ws,
                              size_t ws_size, hipStream_t stream) {
  const float* x     = (const float*)d_in[0];
  const int*   ei    = (const int*)d_in[1];
  const float* w     = (const float*)d_in[2];
  const float* W_gcn = (const float*)d_in[3];
  const float* b_gcn = (const float*)d_in[4];
  const float* Wl    = (const float*)d_in[5];
  const float* bl    = (const float*)d_in[6];
  const float* Wr    = (const float*)d_in[7];
  const float* W_gat = (const float*)d_in[8];
  const float* att_s = (const float*)d_in[9];
  const float* att_d = (const float*)d_in[10];
  const float* b_gat = (const float*)d_in[11];
  const float* Wq    = (const float*)d_in[12];
  const float* bq    = (const float*)d_in[13];
  const float* Wk    = (const float*)d_in[14];
  const float* bk    = (const float*)d_in[15];
  const float* Wv    = (const float*)d_in[16];
  const float* bv    = (const float*)d_in[17];
  const float* Wsk   = (const float*)d_in[18];
  const float* bsk   = (const float*)d_in[19];
  float* out = (float*)d_out;
  float* ws  = (float*)d_ws;

  const int* src = ei;
  const int* dst = ei + EE;

  // workspace layout (float-unit offsets)
  ushort_t* Hb     = (ushort_t*)ws;                       // 128N fl
  ushort_t* ensb   = (ushort_t*)(ws + (size_t)128 * NN);  // 32N fl
  float*    a_s    = ws + (size_t)160 * NN;               // N
  float*    a_d    = ws + (size_t)161 * NN;               // N
  float*    dinv   = ws + (size_t)162 * NN;               // N
  ushort_t* qkvsb  = (ushort_t*)(ws + (size_t)163 * NN);  // 80N fl
  ushort_t* xb     = (ushort_t*)(ws + (size_t)243 * NN);  // 64N fl
  ushort_t* WtA    = (ushort_t*)(ws + (size_t)307 * NN);  // 16384 fl
  ushort_t* WtB    = (ushort_t*)(ws + (size_t)307 * NN + 16384);  // 5120 fl
  float*    bcat   = ws + (size_t)307 * NN + 21504;       // 160 fl
  float*    escore = ws + (size_t)307 * NN + 21664;       // EE fl
  float2*   edata  = (float2*)(ws + (size_t)307 * NN + 21664 + EE);  // 2EE fl
  int*      ibase  = (int*)(ws + (size_t)307 * NN + 21664 + 3 * (size_t)EE);
  int*      cnt    = ibase;                               // N
  int*      offs   = ibase + NN;                          // N
  int*      srcidx = ibase + 2 * NN;                      // EE
  int*      dsts   = ibase + 2 * NN + EE;                 // EE
  int*      erank  = ibase + 2 * NN + 2 * EE;             // EE
  int*      esorted= ibase + 2 * NN + 3 * EE;             // EE
  int*      bsum   = ibase + 2 * NN + 4 * EE;             // NBLK
  int*      cntR   = ibase + 2 * NN + 4 * EE + 256;       // 8N
  int*      base8  = cntR + (size_t)NREP * NN;            // 8N

  hipMemsetAsync(cntR, 0, (size_t)NREP * NN * sizeof(int), stream);

  k_prep<<<PREP_CAST + PREP_W + PREP_HIST, 256, 0, stream>>>(
      x, dst, W_gcn, Wl, W_gat, Wr, Wq, Wk, Wv, Wsk, bq, bk, bv, bsk, xb, WtA,
      WtB, bcat, cntR, erank);

  dim3 gA((NN + 63) / 64, 4);
  k_gemmA<<<gA, 256, 0, stream>>>(xb, WtA, att_s, att_d, Hb, a_s, a_d);
  k_bsum<<<NBLK, SCB, 0, stream>>>(cntR, bsum);
  k_scanapply<<<NBLK, SCB, 0, stream>>>(cntR, bsum, cnt, offs, base8, dinv);
  k_sc1<<<(EE + 255) / 256, 256, 0, stream>>>(dst, erank, base8, esorted);
  k_sc2<<<(EE + 255) / 256, 256, 0, stream>>>(esorted, src, dst, a_s, a_d,
                                              dinv, srcidx, dsts, edata);
  k_agg1<<<(NN + 3) / 4, 256, 0, stream>>>(srcidx, offs, cnt, Hb, edata, dinv,
                                           a_s, a_d, b_gcn, bl, b_gat, w, ensb);
  k_gemmB<<<(NN + 63) / 64, 256, 0, stream>>>(ensb, WtB, bcat, qkvsb);
  k_score<<<(EE * 8 + 255) / 256, 256, 0, stream>>>(srcidx, dsts, qkvsb,
                                                    escore);
  k_agg2<<<(NN + 3) / 4, 256, 0, stream>>>(srcidx, offs, cnt, qkvsb, escore,
                                           out);
}

// Round 12
// 217.082 us; speedup vs baseline: 1.0137x; 1.0120x over previous
//
#include <hip/hip_runtime.h>
#include <math.h>

#define NN 50000
#define EE 800000
#define FIN 128
#define HID 64
#define CL 40
#define SCB 256
#define NBLK ((NN + SCB - 1) / SCB)  // 196
#define NREP 8

typedef unsigned short ushort_t;
typedef unsigned int uint_t;
typedef float f32x4 __attribute__((ext_vector_type(4)));
typedef short s16x8 __attribute__((ext_vector_type(8)));

__device__ __forceinline__ ushort_t f2bf(float f) {
  uint_t u = __float_as_uint(f);
  u = (u + 0x7FFFu + ((u >> 16) & 1u)) >> 16;  // RNE
  return (ushort_t)u;
}
__device__ __forceinline__ uint_t f2bf2(float lo, float hi) {
  return (uint_t)f2bf(lo) | ((uint_t)f2bf(hi) << 16);
}
__device__ __forceinline__ float bf2f(ushort_t s) {
  return __uint_as_float(((uint_t)s) << 16);
}
__device__ __forceinline__ float bflo(uint_t u) {
  return __uint_as_float(u << 16);
}
__device__ __forceinline__ float bfhi(uint_t u) {
  return __uint_as_float(u & 0xFFFF0000u);
}

__device__ __forceinline__ int wave_sum_i(int v) {
#pragma unroll
  for (int off = 32; off > 0; off >>= 1) v += __shfl_xor(v, off, 64);
  return v;
}
__device__ __forceinline__ float half_sum(float v) {  // within 32-lane half
#pragma unroll
  for (int off = 16; off > 0; off >>= 1) v += __shfl_xor(v, off, 64);
  return v;
}
__device__ __forceinline__ float half_max(float v) {
#pragma unroll
  for (int off = 16; off > 0; off >>= 1) v = fmaxf(v, __shfl_xor(v, off, 64));
  return v;
}
__device__ __forceinline__ float gelu_exact(float x) {
  return 0.5f * x * (1.0f + erff(x * 0.70710678118654752f));
}
__device__ __forceinline__ float leaky02(float x) {
  return x >= 0.f ? x : 0.2f * x;
}

// ---------------- fused prep: castx | prepw | hist(XCD-local replica) ----------
#define PREP_CAST 6250   // NN*FIN/4 / 256
#define PREP_W 169       // ceil(43168/256)
#define PREP_HIST 3125   // EE/256
__global__ __launch_bounds__(256) void k_prep(
    const float* __restrict__ x, const int* __restrict__ dst,
    const float* __restrict__ W0, const float* __restrict__ W1,
    const float* __restrict__ W2, const float* __restrict__ W3,
    const float* __restrict__ Q0, const float* __restrict__ Q1,
    const float* __restrict__ Q2, const float* __restrict__ Q3,
    const float* __restrict__ b0, const float* __restrict__ b1,
    const float* __restrict__ b2, const float* __restrict__ b3,
    ushort_t* __restrict__ xb, ushort_t* __restrict__ WtA,
    ushort_t* __restrict__ WtB, float* __restrict__ bcat,
    int* __restrict__ cntR, int* __restrict__ erank) {
  int b = blockIdx.x, t = threadIdx.x;
  if (b < PREP_CAST) {
    int i = b * 256 + t;
    if (i < NN * FIN / 4) {
      float4 v = ((const float4*)x)[i];
      ushort4 o;
      o.x = f2bf(v.x); o.y = f2bf(v.y); o.z = f2bf(v.z); o.w = f2bf(v.w);
      ((ushort4*)xb)[i] = o;
    }
  } else if (b < PREP_CAST + PREP_W) {
    int idx = (b - PREP_CAST) * 256 + t;
    if (idx < 32768) {
      int m = idx >> 13, r = idx & 8191, c = r >> 7, k = r & 127;
      const float* W = (m == 0) ? W0 : (m == 1) ? W1 : (m == 2) ? W2 : W3;
      WtA[idx] = f2bf(W[k * HID + c]);
    } else if (idx < 43008) {
      int j = idx - 32768;
      int c = j >> 6, k = j & 63;
      int mm = c / CL, cc = c % CL;
      const float* W = (mm == 0) ? Q0 : (mm == 1) ? Q1 : (mm == 2) ? Q2 : Q3;
      WtB[j] = f2bf(W[k * CL + cc]);
    } else if (idx < 43168) {
      int c = idx - 43008;
      int mm = c / CL, cc = c % CL;
      const float* bb = (mm == 0) ? b0 : (mm == 1) ? b1 : (mm == 2) ? b2 : b3;
      bcat[c] = bb[cc];
    }
  } else {
    int hb = b - PREP_CAST - PREP_W;  // hist block index
    int e = hb * 256 + t;
    if (e < EE) {
      // replica chosen per-BLOCK so each replica is touched by (mostly) one
      // XCD under round-robin dispatch -> atomics stay XCD-L2-local.
      int r = hb & (NREP - 1);  // == (e >> 8) & 7
      erank[e] = atomicAdd(&cntR[(size_t)r * NN + dst[e]], 1);
    }
  }
}

// ---------------- MFMA GEMM A (+fused att scalars on m==2) ---------------------
__global__ __launch_bounds__(256) void k_gemmA(
    const ushort_t* __restrict__ xb, const ushort_t* __restrict__ WtA,
    const float* __restrict__ attS, const float* __restrict__ attD,
    ushort_t* __restrict__ Hb, float* __restrict__ a_s,
    float* __restrict__ a_d) {
  __shared__ __align__(16) ushort_t wlds[64 * 136];  // [c][k] padded +8
  const int t = threadIdx.x;
  const int m = blockIdx.y;
  for (int idx = t; idx < 64 * 16; idx += 256) {
    int c = idx >> 4, ch = idx & 15;
    *(uint4*)&wlds[c * 136 + ch * 8] =
        *(const uint4*)(WtA + m * 8192 + c * 128 + ch * 8);
  }
  __syncthreads();
  const int wv = t >> 6, l = t & 63;
  const int lr = l & 15, lg = l >> 4;
  const int rbase = blockIdx.x * 64 + wv * 16;
  int arow = rbase + lr;
  int arowc = arow < NN ? arow : NN - 1;
  const ushort_t* ap = xb + (size_t)arowc * 128 + lg * 8;
  f32x4 acc[4] = {};
#pragma unroll
  for (int ks = 0; ks < 4; ++ks) {
    s16x8 af = *(const s16x8*)(ap + ks * 32);
#pragma unroll
    for (int n = 0; n < 4; ++n) {
      s16x8 bf = *(const s16x8*)&wlds[(n * 16 + lr) * 136 + ks * 32 + lg * 8];
      acc[n] = __builtin_amdgcn_mfma_f32_16x16x32_bf16(af, bf, acc[n], 0, 0, 0);
    }
  }
#pragma unroll
  for (int n = 0; n < 4; ++n) {
#pragma unroll
    for (int j = 0; j < 4; ++j) {
      int orow = rbase + lg * 4 + j;
      if (orow < NN)
        Hb[(size_t)orow * 256 + m * 64 + n * 16 + lr] = f2bf(acc[n][j]);
    }
  }
  if (m == 2) {  // GAT block: a_s/a_d from fp32 acc. col = n*16+lr, row=lg*4+j
    float sat[4], dat[4];
#pragma unroll
    for (int n = 0; n < 4; ++n) {
      sat[n] = attS[n * 16 + lr];
      dat[n] = attD[n * 16 + lr];
    }
#pragma unroll
    for (int j = 0; j < 4; ++j) {
      float ps = 0.f, pd = 0.f;
#pragma unroll
      for (int n = 0; n < 4; ++n) {
        ps = fmaf(acc[n][j], sat[n], ps);
        pd = fmaf(acc[n][j], dat[n], pd);
      }
#pragma unroll
      for (int off = 1; off < 16; off <<= 1) {
        ps += __shfl_xor(ps, off, 64);
        pd += __shfl_xor(pd, off, 64);
      }
      int orow = rbase + lg * 4 + j;
      if (lr == 0 && orow < NN) { a_s[orow] = ps; a_d[orow] = pd; }
    }
  }
}

// ---------------- block sums of replica counts ---------------------------------
__global__ __launch_bounds__(SCB) void k_bsum(const int* __restrict__ cntR,
                                              int* __restrict__ bsum) {
  __shared__ int wsm[4];
  int i = blockIdx.x * SCB + threadIdx.x;
  int v = 0;
  if (i < NN) {
#pragma unroll
    for (int r = 0; r < NREP; ++r) v += cntR[(size_t)r * NN + i];
  }
  int s = wave_sum_i(v);
  int lane = threadIdx.x & 63, wv = threadIdx.x >> 6;
  if (lane == 0) wsm[wv] = s;
  __syncthreads();
  if (threadIdx.x == 0) bsum[blockIdx.x] = wsm[0] + wsm[1] + wsm[2] + wsm[3];
}

// ---------------- fused bscan+apply + replica-base computation -----------------
__global__ __launch_bounds__(SCB) void k_scanapply(
    const int* __restrict__ cntR, const int* __restrict__ bsum,
    int* __restrict__ cnt, int* __restrict__ offs, int* __restrict__ base8,
    float* __restrict__ dinv) {
  __shared__ int ts[SCB];
  __shared__ int wred[4];
  int b = blockIdx.x, t = threadIdx.x;
  int pv = (t < b) ? bsum[t] : 0;  // b<=195, t<b implies t<196=NBLK
  int ps = wave_sum_i(pv);
  int lane = t & 63, wv = t >> 6;
  if (lane == 0) wred[wv] = ps;
  int i = b * SCB + t;
  int cr[NREP];
  int v = 0;
  if (i < NN) {
#pragma unroll
    for (int r = 0; r < NREP; ++r) {
      cr[r] = cntR[(size_t)r * NN + i];
      v += cr[r];
    }
  }
  ts[t] = v;
  __syncthreads();
  int prefix = wred[0] + wred[1] + wred[2] + wred[3];
  for (int off = 1; off < SCB; off <<= 1) {
    int u = (t >= off) ? ts[t - off] : 0;
    __syncthreads();
    ts[t] += u;
    __syncthreads();
  }
  if (i < NN) {
    int ex = ts[t] - v + prefix;
    offs[i] = ex;
    cnt[i] = v;
    dinv[i] = rsqrtf((float)v + 1.0f);
    int run = ex;
#pragma unroll
    for (int r = 0; r < NREP; ++r) {
      base8[(size_t)i * NREP + r] = run;
      run += cr[r];
    }
  }
}

// ---------------- scatter pass 1: inverse permutation only (4B/edge) -----------
__global__ __launch_bounds__(256) void k_sc1(const int* __restrict__ dst,
                                             const int* __restrict__ erank,
                                             const int* __restrict__ base8,
                                             int* __restrict__ esorted) {
  int e = blockIdx.x * blockDim.x + threadIdx.x;
  if (e < EE) {
    int d = dst[e];
    int r = (e >> 8) & (NREP - 1);  // must match k_prep's replica choice
    esorted[base8[(size_t)d * NREP + r] + erank[e]] = e;
  }
}

// ---------------- scatter pass 2: p-coalesced fill of sorted arrays ------------
__global__ __launch_bounds__(256) void k_sc2(
    const int* __restrict__ esorted, const int* __restrict__ src,
    const int* __restrict__ dst, const float* __restrict__ a_s,
    const float* __restrict__ a_d, const float* __restrict__ dinv,
    int* __restrict__ srcidx, int* __restrict__ dsts,
    float2* __restrict__ edata) {
  int p = blockIdx.x * blockDim.x + threadIdx.x;
  if (p < EE) {
    int e = esorted[p];
    int s = src[e], d = dst[e];
    srcidx[p] = s;
    dsts[p] = d;
    float ex = __expf(leaky02(a_s[s] + a_d[d]));
    edata[p] = make_float2(dinv[s] * dinv[d], ex);
  }
}

// ---------------- fused GCN+SAGE+GAT aggregation + gelu ensemble ---------------
__global__ __launch_bounds__(256) void k_agg1(
    const int* __restrict__ srcidx, const int* __restrict__ offs,
    const int* __restrict__ cnt, const ushort_t* __restrict__ Hb,
    const float2* __restrict__ edata, const float* __restrict__ dinv,
    const float* __restrict__ a_s, const float* __restrict__ a_d,
    const float* __restrict__ b_gcn, const float* __restrict__ bl,
    const float* __restrict__ b_gat, const float* __restrict__ w,
    ushort_t* __restrict__ ensb) {
  int node = (blockIdx.x * blockDim.x + threadIdx.x) >> 6;
  int lane = threadIdx.x & 63;
  if (node >= NN) return;
  const int half = lane >> 5;
  const int fl = lane & 31;
  int beg = offs[node];
  int c = cnt[node];
  int end = beg + c;
  float ag0 = 0.f, ag1 = 0.f, as0 = 0.f, as1 = 0.f, aa0 = 0.f, aa1 = 0.f,
        dg = 0.f;
  int p = beg + half;
  for (; p + 6 < end; p += 8) {
    int sA = srcidx[p], sB = srcidx[p + 2], sC = srcidx[p + 4],
        sD = srcidx[p + 6];
    float2 eA = edata[p], eB = edata[p + 2], eC = edata[p + 4],
           eD = edata[p + 6];
    const uint_t* hA = (const uint_t*)(Hb + (size_t)sA * 256);
    const uint_t* hB = (const uint_t*)(Hb + (size_t)sB * 256);
    const uint_t* hC = (const uint_t*)(Hb + (size_t)sC * 256);
    const uint_t* hD = (const uint_t*)(Hb + (size_t)sD * 256);
    uint_t gA = hA[fl], qA = hA[32 + fl], tA = hA[64 + fl];
    uint_t gB = hB[fl], qB = hB[32 + fl], tB = hB[64 + fl];
    uint_t gC = hC[fl], qC = hC[32 + fl], tC = hC[64 + fl];
    uint_t gD = hD[fl], qD = hD[32 + fl], tD = hD[64 + fl];
    ag0 = fmaf(bflo(gA), eA.x, ag0); ag1 = fmaf(bfhi(gA), eA.x, ag1);
    ag0 = fmaf(bflo(gB), eB.x, ag0); ag1 = fmaf(bfhi(gB), eB.x, ag1);
    ag0 = fmaf(bflo(gC), eC.x, ag0); ag1 = fmaf(bfhi(gC), eC.x, ag1);
    ag0 = fmaf(bflo(gD), eD.x, ag0); ag1 = fmaf(bfhi(gD), eD.x, ag1);
    as0 += (bflo(qA) + bflo(qB)) + (bflo(qC) + bflo(qD));
    as1 += (bfhi(qA) + bfhi(qB)) + (bfhi(qC) + bfhi(qD));
    aa0 = fmaf(bflo(tA), eA.y, aa0); aa1 = fmaf(bfhi(tA), eA.y, aa1);
    aa0 = fmaf(bflo(tB), eB.y, aa0); aa1 = fmaf(bfhi(tB), eB.y, aa1);
    aa0 = fmaf(bflo(tC), eC.y, aa0); aa1 = fmaf(bfhi(tC), eC.y, aa1);
    aa0 = fmaf(bflo(tD), eD.y, aa0); aa1 = fmaf(bfhi(tD), eD.y, aa1);
    dg += (eA.y + eB.y) + (eC.y + eD.y);
  }
  for (; p < end; p += 2) {
    int sA = srcidx[p];
    float2 eA = edata[p];
    const uint_t* hA = (const uint_t*)(Hb + (size_t)sA * 256);
    uint_t gA = hA[fl], qA = hA[32 + fl], tA = hA[64 + fl];
    ag0 = fmaf(bflo(gA), eA.x, ag0); ag1 = fmaf(bfhi(gA), eA.x, ag1);
    as0 += bflo(qA);                 as1 += bfhi(qA);
    aa0 = fmaf(bflo(tA), eA.y, aa0); aa1 = fmaf(bfhi(tA), eA.y, aa1);
    dg += eA.y;
  }
  // fold halves
  ag0 += __shfl_xor(ag0, 32, 64); ag1 += __shfl_xor(ag1, 32, 64);
  as0 += __shfl_xor(as0, 32, 64); as1 += __shfl_xor(as1, 32, 64);
  aa0 += __shfl_xor(aa0, 32, 64); aa1 += __shfl_xor(aa1, 32, 64);
  dg += __shfl_xor(dg, 32, 64);
  // epilogue
  float dd = dinv[node];
  float exl = __expf(leaky02(a_s[node] + a_d[node]));
  const uint_t* hd = (const uint_t*)(Hb + (size_t)node * 256);
  uint_t hg = hd[fl], ht = hd[64 + fl], hr = hd[96 + fl];
  float2 bg = ((const float2*)b_gcn)[fl];
  float2 bs = ((const float2*)bl)[fl];
  float2 ba = ((const float2*)b_gat)[fl];
  float dd2 = dd * dd;
  float cinv = 1.0f / fmaxf((float)c, 1.0f);
  float gdi = 1.0f / (dg + exl + 1e-16f);
  float g0 = ag0 + dd2 * bflo(hg) + bg.x;
  float g1 = ag1 + dd2 * bfhi(hg) + bg.y;
  float s0 = as0 * cinv + bs.x + bflo(hr);
  float s1 = as1 * cinv + bs.y + bfhi(hr);
  float t0 = (aa0 + exl * bflo(ht)) * gdi + ba.x;
  float t1 = (aa1 + exl * bfhi(ht)) * gdi + ba.y;
  float w0 = w[0], w1 = w[1], w2 = w[2];
  float e0 = w0 * gelu_exact(g0) + w1 * gelu_exact(s0) + w2 * gelu_exact(t0);
  float e1 = w0 * gelu_exact(g1) + w1 * gelu_exact(s1) + w2 * gelu_exact(t1);
  if (half == 0) ((uint_t*)ensb)[(size_t)node * 32 + fl] = f2bf2(e0, e1);
}

// ---------------- MFMA GEMM B: QKVSb = bf16(ens @ [Wq|Wk|Wv|Wskip] + bias) -----
__global__ __launch_bounds__(256) void k_gemmB(
    const ushort_t* __restrict__ ensb, const ushort_t* __restrict__ WtB,
    const float* __restrict__ bcat, ushort_t* __restrict__ QKVSb) {
  __shared__ __align__(16) ushort_t wb[160 * 72];  // [c][k] padded +8
  __shared__ float bsh[160];
  const int t = threadIdx.x;
  for (int idx = t; idx < 160 * 8; idx += 256) {
    int c = idx >> 3, ch = idx & 7;
    *(uint4*)&wb[c * 72 + ch * 8] = *(const uint4*)(WtB + c * 64 + ch * 8);
  }
  if (t < 160) bsh[t] = bcat[t];
  __syncthreads();
  const int wv = t >> 6, l = t & 63;
  const int lr = l & 15, lg = l >> 4;
  const int rbase = blockIdx.x * 64 + wv * 16;
  int arow = rbase + lr;
  int arowc = arow < NN ? arow : NN - 1;
  const ushort_t* ap = ensb + (size_t)arowc * 64 + lg * 8;
  f32x4 acc[10] = {};
#pragma unroll
  for (int ks = 0; ks < 2; ++ks) {
    s16x8 af = *(const s16x8*)(ap + ks * 32);
#pragma unroll
    for (int n = 0; n < 10; ++n) {
      s16x8 bf = *(const s16x8*)&wb[(n * 16 + lr) * 72 + ks * 32 + lg * 8];
      acc[n] = __builtin_amdgcn_mfma_f32_16x16x32_bf16(af, bf, acc[n], 0, 0, 0);
    }
  }
#pragma unroll
  for (int n = 0; n < 10; ++n) {
    int col = n * 16 + lr;
#pragma unroll
    for (int j = 0; j < 4; ++j) {
      int orow = rbase + lg * 4 + j;
      if (orow < NN)
        QKVSb[(size_t)orow * 160 + col] = f2bf(acc[n][j] + bsh[col]);
    }
  }
}

// ---------------- edge-parallel transformer scores (8 lanes/edge) --------------
__global__ __launch_bounds__(256) void k_score(
    const int* __restrict__ srcidx, const int* __restrict__ dsts,
    const ushort_t* __restrict__ QKVSb, float* __restrict__ escore) {
  int p = (blockIdx.x * 256 + threadIdx.x) >> 3;
  int l = threadIdx.x & 7;
  if (p >= EE) return;
  int s = srcidx[p], d = dsts[p];
  float part = 0.f;
  if (l < 5) {
    const uint4 qv = *(const uint4*)(QKVSb + (size_t)d * 160 + l * 8);
    const uint4 kv = *(const uint4*)(QKVSb + (size_t)s * 160 + 40 + l * 8);
    part = bflo(qv.x) * bflo(kv.x);
    part = fmaf(bfhi(qv.x), bfhi(kv.x), part);
    part = fmaf(bflo(qv.y), bflo(kv.y), part);
    part = fmaf(bfhi(qv.y), bfhi(kv.y), part);
    part = fmaf(bflo(qv.z), bflo(kv.z), part);
    part = fmaf(bfhi(qv.z), bfhi(kv.z), part);
    part = fmaf(bflo(qv.w), bflo(kv.w), part);
    part = fmaf(bfhi(qv.w), bfhi(kv.w), part);
  }
  part += __shfl_xor(part, 1, 64);
  part += __shfl_xor(part, 2, 64);
  part += __shfl_xor(part, 4, 64);
  if (l == 0) escore[p] = __expf(part * 0.15811388300841897f);
}

// ---------------- transformer aggregation + log_softmax ------------------------
__global__ __launch_bounds__(256) void k_agg2(
    const int* __restrict__ srcidx, const int* __restrict__ offs,
    const int* __restrict__ cnt, const ushort_t* __restrict__ QKVSb,
    const float* __restrict__ escore, float* __restrict__ out) {
  int node = (blockIdx.x * blockDim.x + threadIdx.x) >> 6;
  int lane = threadIdx.x & 63;
  if (node >= NN) return;
  const int half = lane >> 5;
  const int fl = lane & 31;   // feature-pair index (feats 2fl, 2fl+1 of 40)
  const bool valid = fl < 20;
  int beg = offs[node];
  int end = beg + cnt[node];
  float den = 0.f, av0 = 0.f, av1 = 0.f;
  int p = beg + half;
  for (; p + 6 < end; p += 8) {
    int sA = srcidx[p], sB = srcidx[p + 2], sC = srcidx[p + 4],
        sD = srcidx[p + 6];
    float eA = escore[p], eB = escore[p + 2], eC = escore[p + 4],
          eD = escore[p + 6];
    uint_t vA = valid ? ((const uint_t*)(QKVSb + (size_t)sA * 160))[40 + fl] : 0u;
    uint_t vB = valid ? ((const uint_t*)(QKVSb + (size_t)sB * 160))[40 + fl] : 0u;
    uint_t vC = valid ? ((const uint_t*)(QKVSb + (size_t)sC * 160))[40 + fl] : 0u;
    uint_t vD = valid ? ((const uint_t*)(QKVSb + (size_t)sD * 160))[40 + fl] : 0u;
    av0 = fmaf(eA, bflo(vA), av0); av1 = fmaf(eA, bfhi(vA), av1);
    av0 = fmaf(eB, bflo(vB), av0); av1 = fmaf(eB, bfhi(vB), av1);
    av0 = fmaf(eC, bflo(vC), av0); av1 = fmaf(eC, bfhi(vC), av1);
    av0 = fmaf(eD, bflo(vD), av0); av1 = fmaf(eD, bfhi(vD), av1);
    den += (eA + eB) + (eC + eD);
  }
  for (; p < end; p += 2) {
    int sA = srcidx[p];
    float eA = escore[p];
    uint_t vA = valid ? ((const uint_t*)(QKVSb + (size_t)sA * 160))[40 + fl] : 0u;
    av0 = fmaf(eA, bflo(vA), av0); av1 = fmaf(eA, bfhi(vA), av1);
    den += eA;
  }
  // fold halves
  av0 += __shfl_xor(av0, 32, 64);
  av1 += __shfl_xor(av1, 32, 64);
  den += __shfl_xor(den, 32, 64);
  const uint_t* rd = (const uint_t*)(QKVSb + (size_t)node * 160);
  uint_t sk = valid ? rd[60 + fl] : 0u;
  float di = 1.0f / (den + 1e-16f);
  float o0 = valid ? av0 * di + bflo(sk) : -3.0e38f;
  float o1 = valid ? av1 * di + bfhi(sk) : -3.0e38f;
  float m = half_max(fmaxf(o0, o1));
  float eo = valid ? __expf(o0 - m) + __expf(o1 - m) : 0.f;
  float ls = logf(half_sum(eo));
  if (valid && half == 0) {
    float2 r = make_float2(o0 - m - ls, o1 - m - ls);
    ((float2*)out)[(size_t)node * 20 + fl] = r;
  }
}

extern "C" void kernel_launch(void* const* d_in, const int* in_sizes, int n_in,
                              void* d_out, int out_size, void* d_ws,
                              size_t ws_size, hipStream_t stream) {
  const float* x     = (const float*)d_in[0];
  const int*   ei    = (const int*)d_in[1];
  const float* w     = (const float*)d_in[2];
  const float* W_gcn = (const float*)d_in[3];
  const float* b_gcn = (const float*)d_in[4];
  const float* Wl    = (const float*)d_in[5];
  const float* bl    = (const float*)d_in[6];
  const float* Wr    = (const float*)d_in[7];
  const float* W_gat = (const float*)d_in[8];
  const float* att_s = (const float*)d_in[9];
  const float* att_d = (const float*)d_in[10];
  const float* b_gat = (const float*)d_in[11];
  const float* Wq    = (const float*)d_in[12];
  const float* bq    = (const float*)d_in[13];
  const float* Wk    = (const float*)d_in[14];
  const float* bk    = (const float*)d_in[15];
  const float* Wv    = (const float*)d_in[16];
  const float* bv    = (const float*)d_in[17];
  const float* Wsk   = (const float*)d_in[18];
  const float* bsk   = (const float*)d_in[19];
  float* out = (float*)d_out;
  float* ws  = (float*)d_ws;

  const int* src = ei;
  const int* dst = ei + EE;

  // workspace layout (float-unit offsets)
  ushort_t* Hb     = (ushort_t*)ws;                       // 128N fl
  ushort_t* ensb   = (ushort_t*)(ws + (size_t)128 * NN);  // 32N fl
  float*    a_s    = ws + (size_t)160 * NN;               // N
  float*    a_d    = ws + (size_t)161 * NN;               // N
  float*    dinv   = ws + (size_t)162 * NN;               // N
  ushort_t* qkvsb  = (ushort_t*)(ws + (size_t)163 * NN);  // 80N fl
  ushort_t* xb     = (ushort_t*)(ws + (size_t)243 * NN);  // 64N fl
  ushort_t* WtA    = (ushort_t*)(ws + (size_t)307 * NN);  // 16384 fl
  ushort_t* WtB    = (ushort_t*)(ws + (size_t)307 * NN + 16384);  // 5120 fl
  float*    bcat   = ws + (size_t)307 * NN + 21504;       // 160 fl
  float*    escore = ws + (size_t)307 * NN + 21664;       // EE fl
  float2*   edata  = (float2*)(ws + (size_t)307 * NN + 21664 + EE);  // 2EE fl
  int*      ibase  = (int*)(ws + (size_t)307 * NN + 21664 + 3 * (size_t)EE);
  int*      cnt    = ibase;                               // N
  int*      offs   = ibase + NN;                          // N
  int*      srcidx = ibase + 2 * NN;                      // EE
  int*      dsts   = ibase + 2 * NN + EE;                 // EE
  int*      erank  = ibase + 2 * NN + 2 * EE;             // EE
  int*      esorted= ibase + 2 * NN + 3 * EE;             // EE
  int*      bsum   = ibase + 2 * NN + 4 * EE;             // NBLK
  int*      cntR   = ibase + 2 * NN + 4 * EE + 256;       // 8N
  int*      base8  = cntR + (size_t)NREP * NN;            // 8N

  hipMemsetAsync(cntR, 0, (size_t)NREP * NN * sizeof(int), stream);

  k_prep<<<PREP_CAST + PREP_W + PREP_HIST, 256, 0, stream>>>(
      x, dst, W_gcn, Wl, W_gat, Wr, Wq, Wk, Wv, Wsk, bq, bk, bv, bsk, xb, WtA,
      WtB, bcat, cntR, erank);

  dim3 gA((NN + 63) / 64, 4);
  k_gemmA<<<gA, 256, 0, stream>>>(xb, WtA, att_s, att_d, Hb, a_s, a_d);
  k_bsum<<<NBLK, SCB, 0, stream>>>(cntR, bsum);
  k_scanapply<<<NBLK, SCB, 0, stream>>>(cntR, bsum, cnt, offs, base8, dinv);
  k_sc1<<<(EE + 255) / 256, 256, 0, stream>>>(dst, erank, base8, esorted);
  k_sc2<<<(EE + 255) / 256, 256, 0, stream>>>(esorted, src, dst, a_s, a_d,
                                              dinv, srcidx, dsts, edata);
  k_agg1<<<(NN + 3) / 4, 256, 0, stream>>>(srcidx, offs, cnt, Hb, edata, dinv,
                                           a_s, a_d, b_gcn, bl, b_gat, w, ensb);
  k_gemmB<<<(NN + 63) / 64, 256, 0, stream>>>(ensb, WtB, bcat, qkvsb);
  k_score<<<(EE * 8 + 255) / 256, 256, 0, stream>>>(srcidx, dsts, qkvsb,
                                                    escore);
  k_agg2<<<(NN + 3) / 4, 256, 0, stream>>>(srcidx, offs, cnt, qkvsb, escore,
                                           out);
}